// Round 3
// baseline (291.090 us; speedup 1.0000x reference)
//
#include <hip/hip_runtime.h>
#include <hip/hip_bf16.h>
#include <math.h>
#include <float.h>

// TopKTopPSampler: BATCH=256 rows, VOCAB=128000 fp32 logits. Output: int32 index.
// argmax(softmax(masked)/q) over survivors of top-k (k<=64) + top-p pruning.
// Candidates collected in one streaming pass (val >= T=3.0 for N(0,1); retry
// loop for arbitrary inputs); finish per-row in LDS.
// q IS fully streamed (fused with logits pass) ONLY to find exact-zero q:
// ref computes probs/q, so q==0 at a masked token -> 0/0=NaN, and numpy/JAX
// argmax returns the FIRST NaN index; q==0 at a kept token -> +inf. E[#zeros]
// ~4 over the dataset, so this path decides ~4 rows and is mandatory.

#define VOCAB_N 128000
#define CAP  2048   // candidate buffer (expected ~173 at T=3.0)
#define SCAP 160    // survivor buffer (k<=64 plus tie margin)
#define ZCAP 128    // q==0 index buffer (expected 0-2 per row)

__global__ __launch_bounds__(1024)
void topk_topp_sample_kernel(const float* __restrict__ logits,
                             const int*   __restrict__ kArr,
                             const float* __restrict__ pArr,
                             const float* __restrict__ qArr,
                             int*         __restrict__ out)
{
    const int row  = blockIdx.x;
    const int tid  = threadIdx.x;
    const int nthr = blockDim.x;
    const float* __restrict__ lrow = logits + (size_t)row * VOCAB_N;
    const float* __restrict__ qrow = qArr   + (size_t)row * VOCAB_N;

    int kk = kArr[row];
    if (kk < 1)  kk = 1;
    if (kk > 64) kk = 64;
    const float pinv = 1.0f - pArr[row];   // drop prefix with cum <= 1-p

    __shared__ float cval[CAP];
    __shared__ int   cidx[CAP];
    __shared__ float sval[SCAP];
    __shared__ int   sidx[SCAP];
    __shared__ float sv2[SCAP];
    __shared__ int   si2[SCAP];
    __shared__ float sprob[SCAP];
    __shared__ float scum[SCAP];
    __shared__ float sq[SCAP];
    __shared__ int   zidx[ZCAP];
    __shared__ int   cnt;
    __shared__ int   scnt;
    __shared__ int   zcnt;
    __shared__ float Zsh;

    // ---- Phase 1a: fused first pass — logit candidates >= T, and q==0 scan ----
    float T = 3.0f;
    if (tid == 0) { cnt = 0; zcnt = 0; }
    __syncthreads();
    {
        const float4* l4 = (const float4*)lrow;
        const float4* q4 = (const float4*)qrow;
        for (int i = tid; i < VOCAB_N / 4; i += nthr) {
            float4 v  = l4[i];
            float4 qv = q4[i];
            float qmn = fminf(fminf(qv.x, qv.y), fminf(qv.z, qv.w));
            if (qmn == 0.0f) {           // q >= 0 always (Exp(1)); min==0 -> some zero
                int b = i * 4;
                if (qv.x == 0.0f) { int p = atomicAdd(&zcnt, 1); if (p < ZCAP) zidx[p] = b;     }
                if (qv.y == 0.0f) { int p = atomicAdd(&zcnt, 1); if (p < ZCAP) zidx[p] = b + 1; }
                if (qv.z == 0.0f) { int p = atomicAdd(&zcnt, 1); if (p < ZCAP) zidx[p] = b + 2; }
                if (qv.w == 0.0f) { int p = atomicAdd(&zcnt, 1); if (p < ZCAP) zidx[p] = b + 3; }
            }
            float mx = fmaxf(fmaxf(v.x, v.y), fmaxf(v.z, v.w));
            if (mx >= T) {
                int b = i * 4;
                if (v.x >= T) { int p = atomicAdd(&cnt, 1); if (p < CAP) { cval[p] = v.x; cidx[p] = b;     } }
                if (v.y >= T) { int p = atomicAdd(&cnt, 1); if (p < CAP) { cval[p] = v.y; cidx[p] = b + 1; } }
                if (v.z >= T) { int p = atomicAdd(&cnt, 1); if (p < CAP) { cval[p] = v.z; cidx[p] = b + 2; } }
                if (v.w >= T) { int p = atomicAdd(&cnt, 1); if (p < CAP) { cval[p] = v.w; cidx[p] = b + 3; } }
            }
        }
    }
    __syncthreads();
    int c = cnt;

    // ---- Phase 1b: retry (logits only) — unreachable for N(0,1) bench data ----
    for (int attempt = 1; attempt < 64 && !(c >= kk && c <= CAP); ++attempt) {
        if (c < kk) T -= 1.0f; else T += 0.75f;
        __syncthreads();
        if (tid == 0) cnt = 0;
        __syncthreads();
        const float4* l4 = (const float4*)lrow;
        for (int i = tid; i < VOCAB_N / 4; i += nthr) {
            float4 v = l4[i];
            float mx = fmaxf(fmaxf(v.x, v.y), fmaxf(v.z, v.w));
            if (mx >= T) {
                int b = i * 4;
                if (v.x >= T) { int p = atomicAdd(&cnt, 1); if (p < CAP) { cval[p] = v.x; cidx[p] = b;     } }
                if (v.y >= T) { int p = atomicAdd(&cnt, 1); if (p < CAP) { cval[p] = v.y; cidx[p] = b + 1; } }
                if (v.z >= T) { int p = atomicAdd(&cnt, 1); if (p < CAP) { cval[p] = v.z; cidx[p] = b + 2; } }
                if (v.w >= T) { int p = atomicAdd(&cnt, 1); if (p < CAP) { cval[p] = v.w; cidx[p] = b + 3; } }
            }
        }
        __syncthreads();
        c = cnt;
    }
    if (c > CAP) c = CAP;  // safety clamp

    // ---- Phase 2: top-k survivors. strict-greater rank < k  <=>  val >= thr ----
    __syncthreads();
    if (tid == 0) scnt = 0;
    __syncthreads();
    for (int j = tid; j < c; j += nthr) {
        float vj = cval[j];
        int rs = 0;
        for (int j2 = 0; j2 < c; ++j2) rs += (cval[j2] > vj) ? 1 : 0;
        if (rs < kk) {
            int p = atomicAdd(&scnt, 1);
            if (p < SCAP) { sval[p] = vj; sidx[p] = cidx[j]; }
        }
    }
    __syncthreads();
    int s = scnt;
    if (s > SCAP) s = SCAP;

    // ---- Phase 3: sort survivors ascending by (val, idx) ----
    for (int j = tid; j < s; j += nthr) {
        float vj = sval[j]; int ij = sidx[j];
        int pos = 0;
        for (int j2 = 0; j2 < s; ++j2) {
            float v2 = sval[j2]; int i2 = sidx[j2];
            pos += (v2 < vj || (v2 == vj && i2 < ij)) ? 1 : 0;
        }
        sv2[pos] = vj; si2[pos] = ij;
    }
    __syncthreads();

    // ---- Phase 4: softmax probs + sequential ascending cumsum + q gather ----
    const float m = sv2[s - 1];  // global row max
    for (int j = tid; j < s; j += nthr) sprob[j] = expf(sv2[j] - m);
    __syncthreads();
    if (tid == 0) { float Z = 0.f; for (int j = 0; j < s; ++j) Z += sprob[j]; Zsh = Z; }
    __syncthreads();
    const float Z = Zsh;
    for (int j = tid; j < s; j += nthr) sprob[j] = sprob[j] / Z;   // divide first, like ref
    __syncthreads();
    for (int j = tid; j < s; j += nthr) {
        float cm = 0.f;
        for (int j2 = 0; j2 <= j; ++j2) cm += sprob[j2];  // exact ascending fp order
        scum[j] = cm;
    }
    for (int j = tid; j < s; j += nthr) sq[j] = qrow[si2[j]];
    __syncthreads();

    // ---- Phase 5: top-p keep mask + exact numpy argmax(probs/q) semantics ----
    if (tid == 0) {
        // NaN rule: probs/q is NaN at (q==0 AND final-prob==0) positions; numpy
        // argmax returns the FIRST NaN index, beating +inf and all finite.
        int zn = zcnt; if (zn > ZCAP) zn = ZCAP;
        int nanIdx = 0x7fffffff;
        for (int t = 0; t < zn; ++t) {
            int z = zidx[t];
            bool keptMember = false;
            for (int j = 0; j < s; ++j) {
                bool kept = (scum[j] > pinv) || (j == s - 1);
                if (kept && si2[j] == z) { keptMember = true; break; }
            }
            if (!keptMember && z < nanIdx) nanIdx = z;
        }
        if (nanIdx != 0x7fffffff) {
            out[row] = nanIdx;
        } else {
            // kept token with q==0 -> sprob/0 = +inf; > beats finite, ==inf ties
            // resolve to smallest original index — matching first-index argmax.
            float br = -FLT_MAX; int bi = 0x7fffffff;
            for (int j = 0; j < s; ++j) {
                bool kept = (scum[j] > pinv) || (j == s - 1);
                if (!kept) continue;
                float r = sprob[j] / sq[j];
                if (r > br || (r == br && si2[j] < bi)) { br = r; bi = si2[j]; }
            }
            out[row] = bi;
        }
    }
}

extern "C" void kernel_launch(void* const* d_in, const int* in_sizes, int n_in,
                              void* d_out, int out_size, void* d_ws, size_t ws_size,
                              hipStream_t stream) {
    const float* logits = (const float*)d_in[0];
    const int*   k      = (const int*)d_in[1];
    const float* p      = (const float*)d_in[2];
    const float* q      = (const float*)d_in[3];
    int*         out    = (int*)d_out;
    const int batch = out_size;  // 256 rows, one block per row
    topk_topp_sample_kernel<<<batch, 1024, 0, stream>>>(logits, k, p, q, out);
}